// Round 5
// baseline (1150.021 us; speedup 1.0000x reference)
//
#include <hip/hip_runtime.h>
#include <hip/hip_bf16.h>

// Problem constants (BasicRecurrentLayer): B=64, T=1024, F=128, U=256
constexpr int B = 64;
constexpr int T = 1024;
constexpr int F = 128;
constexpr int U = 256;

typedef __fp16 f16x8 __attribute__((ext_vector_type(8)));
typedef float  f32x4 __attribute__((ext_vector_type(4)));

// ---------------------------------------------------------------------------
// h storage helpers (fp32 if workspace fits 64 MB, else bf16 = 32 MB)
// ---------------------------------------------------------------------------
__device__ __forceinline__ float toF32(float v) { return v; }
__device__ __forceinline__ float toF32(__hip_bfloat16 v) { return __bfloat162float(v); }

__device__ __forceinline__ void store8(float* p, const float* a) {
    ((float4*)p)[0] = make_float4(a[0], a[1], a[2], a[3]);
    ((float4*)p)[1] = make_float4(a[4], a[5], a[6], a[7]);
}
__device__ __forceinline__ void store8(__hip_bfloat16* p, const float* a) {
    unsigned int v[4];
    #pragma unroll
    for (int i = 0; i < 4; ++i) {
        __hip_bfloat16 lo = __float2bfloat16(a[2 * i]);
        __hip_bfloat16 hi = __float2bfloat16(a[2 * i + 1]);
        unsigned short lob = *(unsigned short*)&lo;
        unsigned short hib = *(unsigned short*)&hi;
        v[i] = (unsigned int)lob | ((unsigned int)hib << 16);
    }
    ((uint4*)p)[0] = make_uint4(v[0], v[1], v[2], v[3]);
}

// Exact identity tanh(x) = 1 - 2/(1+e^{2x}); e^{2x} = exp2(x*2*log2(e)).
// v_exp_f32 + v_rcp_f32, ~1e-6 abs err, correct saturation at +-1 (also for
// +-inf inputs from pad rows), no branches.
__device__ __forceinline__ float tanh_fast(float x) {
    float e = __builtin_amdgcn_exp2f(x * 2.885390081777927f);
    float r = __builtin_amdgcn_rcpf(1.0f + e);
    return fmaf(-2.0f, r, 1.0f);
}

// lgkmcnt(0) only (vmcnt=63, expcnt=7 -> no wait): 0xC07F. Raw barrier that
// does NOT drain vmcnt, so h-prefetch / out-stores stay in flight across it.
__device__ __forceinline__ void lds_barrier() {
    __builtin_amdgcn_s_waitcnt(0xC07F);
    asm volatile("" ::: "memory");
    __builtin_amdgcn_s_barrier();
    asm volatile("" ::: "memory");
}

// ---------------------------------------------------------------------------
// Kernel 1: projection  h[t, b, u] = sum_f inputs[b, t, f] * R[f, u]
// Grid (T/64, U/64, B), 512 threads (8 waves). lane = t-row r; wave owns 8 u.
// A-tile (64x128 fp32, 32 KB) in LDS, XOR-swizzled float4 slots (conflict-
// free b128 read+write). R comes in as wave-uniform scalar loads (SGPRs),
// ping-pong prefetched one k4-group ahead to hide s_load latency.
// (Round-0 version verbatim, ~103 us.)
// ---------------------------------------------------------------------------
template <typename HT>
__global__ __launch_bounds__(512, 2) void proj_kernel(
    const float* __restrict__ in,   // [B, T, F]
    const float* __restrict__ Rm,   // [F, U]
    HT* __restrict__ h)             // [T, B, U]
{
    const int t0   = blockIdx.x * 64;
    const int u0b  = blockIdx.y * 64;
    const int b    = blockIdx.z;
    const int tid  = threadIdx.x;
    const int lane = tid & 63;      // = r (t-row within tile)
    const int wv   = tid >> 6;      // 0..7
    const int u0   = __builtin_amdgcn_readfirstlane(u0b + wv * 8);

    __shared__ float4 a4[64 * 32];  // 32 KB, swizzled

    const float4* src = (const float4*)(in + ((size_t)b * T + t0) * F);
    #pragma unroll
    for (int it = 0; it < 4; ++it) {
        int f  = tid + it * 512;        // 0..2047 coalesced
        int r  = f >> 5;
        int k4 = f & 31;
        a4[(r << 5) | (k4 ^ (r & 31))] = src[f];
    }
    __syncthreads();

    const float* Rp = Rm + u0;      // wave-uniform -> scalar loads
    float acc[8];
    #pragma unroll
    for (int j = 0; j < 8; ++j) acc[j] = 0.f;

    float ra[32], rb[32];           // uniform (SGPR) ping-pong R buffers
    #pragma unroll
    for (int kk = 0; kk < 4; ++kk)
        #pragma unroll
        for (int j = 0; j < 8; ++j)
            ra[kk * 8 + j] = Rp[(size_t)kk * U + j];

    const int r = lane;
    #pragma unroll
    for (int k4 = 0; k4 < 32; k4 += 2) {
        // prefetch k4+1 into rb
        #pragma unroll
        for (int kk = 0; kk < 4; ++kk)
            #pragma unroll
            for (int j = 0; j < 8; ++j)
                rb[kk * 8 + j] = Rp[(size_t)((k4 + 1) * 4 + kk) * U + j];

        float4 av = a4[(r << 5) | (k4 ^ (r & 31))];
        #pragma unroll
        for (int j = 0; j < 8; ++j) {
            acc[j] = fmaf(av.x, ra[0 * 8 + j], acc[j]);
            acc[j] = fmaf(av.y, ra[1 * 8 + j], acc[j]);
            acc[j] = fmaf(av.z, ra[2 * 8 + j], acc[j]);
            acc[j] = fmaf(av.w, ra[3 * 8 + j], acc[j]);
        }

        // prefetch k4+2 into ra
        if (k4 + 2 < 32) {
            #pragma unroll
            for (int kk = 0; kk < 4; ++kk)
                #pragma unroll
                for (int j = 0; j < 8; ++j)
                    ra[kk * 8 + j] = Rp[(size_t)((k4 + 2) * 4 + kk) * U + j];
        }

        float4 av2 = a4[(r << 5) | ((k4 + 1) ^ (r & 31))];
        #pragma unroll
        for (int j = 0; j < 8; ++j) {
            acc[j] = fmaf(av2.x, rb[0 * 8 + j], acc[j]);
            acc[j] = fmaf(av2.y, rb[1 * 8 + j], acc[j]);
            acc[j] = fmaf(av2.z, rb[2 * 8 + j], acc[j]);
            acc[j] = fmaf(av2.w, rb[3 * 8 + j], acc[j]);
        }
    }

    HT* hp = h + ((size_t)(t0 + r) * B + b) * U + u0;
    store8(hp, acc);
}

// ---------------------------------------------------------------------------
// Kernel 2: recurrence via MFMA. Grid 8 (8 batch rows per block), 512 threads
// = 8 waves. State S[16][256] fp16 in LDS (rows 0-7 real, 8-15 pad),
// double-buffered, XOR-swizzled (elem ^ ((row&7)<<3)) so the stride-512B A
// fragment reads are ~2-way (free).
//
// Per step: X[16,256] = S @ W via v_mfma_f32_16x16x32_f16 (f32 accum; fp16
// RNE inputs validated in round 4 at zero added error). Wave wv owns N-tiles
// {2wv, 2wv+1}; W B-fragments (128 fp16 = 64 VGPR) preloaded once.
// Fragment maps: A row=lane&15, k=(lane>>4)*8+j (blocked); B col=lane&15,
// same k; C/D col=lane&15, row=(lane>>4)*4+reg (m89 HW-verified).
// acc is initialized with h[t]+bias (C-in of the first MFMA), so the h-add
// is free. Epilogue: 8 tanh/lane, out-stores (lanes with real rows), fp16
// pack + 8 ds_write_b16 into the other S buffer, ONE lgkm-only barrier.
// h prefetched 2 steps ahead into even/odd register sets (hE/hO); the raw
// barrier never drains vmcnt so loads/stores span steps.
// Pad rows (8-15) run a bounded dummy recurrence (tanh keeps them in [-1,1]).
// ---------------------------------------------------------------------------
template <typename HT>
__global__ __launch_bounds__(512, 2) void rnn_kernel(
    const HT* __restrict__ h,        // [T, B, U]
    const float* __restrict__ Wm,    // [U, U]
    const float* __restrict__ bias,  // [U]
    const float* __restrict__ x0,    // [U]
    float* __restrict__ out)         // [T, B, U]
{
    const int b0  = blockIdx.x * 8;   // this block's 8 real batch rows
    const int tid = threadIdx.x;
    const int l   = tid & 63;
    const int wv  = tid >> 6;         // 0..7
    const int lr  = l & 15;
    const int lg  = l >> 4;           // 0..3
    const int n0  = wv * 32;          // wave's N-tiles: cols n0..n0+15, n0+16..n0+31

    __shared__ __fp16 sbuf[2][16][256];

    // B fragments (W), fp16 RNE: bf{0,1}[kt][jj] = W[kt*32+lg*8+jj][n0(+16)+lr]
    f16x8 bf0[8], bf1[8];
    #pragma unroll
    for (int kt = 0; kt < 8; ++kt) {
        #pragma unroll
        for (int jj = 0; jj < 8; ++jj) {
            const size_t k = (size_t)(kt * 32 + lg * 8 + jj);
            bf0[kt][jj] = (__fp16)Wm[k * U + n0 + lr];
            bf1[kt][jj] = (__fp16)Wm[k * U + n0 + 16 + lr];
        }
    }

    const bool  actv = (lg < 2);            // lanes owning real rows (m = lg*4+r < 8)
    const float bv0  = bias[n0 + lr];
    const float bv1  = bias[n0 + 16 + lr];

    // init S = x0 for all 16 rows (pad rows run a bounded dummy recurrence)
    {
        const int m  = tid >> 5;            // 0..15
        const int ub = (tid & 31) * 8;      // 0..248
        #pragma unroll
        for (int j = 0; j < 8; ++j)
            sbuf[0][m][(ub + j) ^ ((m & 7) << 3)] = (__fp16)x0[ub + j];
    }
    __syncthreads();

    const size_t tstride = (size_t)B * U;               // 16384
    const size_t base    = (size_t)(b0 + lg * 4) * U + lr;  // + r*U + n0{,+16}

    // h prefetch, 2 steps deep via even/odd sets; layout [nt*4 + r]
    HT hE[8], hO[8];
    if (actv) {
        #pragma unroll
        for (int r = 0; r < 4; ++r) {
            hE[r]     = h[base + (size_t)r * U + n0];
            hE[4 + r] = h[base + (size_t)r * U + n0 + 16];
            hO[r]     = h[tstride + base + (size_t)r * U + n0];
            hO[4 + r] = h[tstride + base + (size_t)r * U + n0 + 16];
        }
    }

#define RNN_STEP(t, hX, RB, WB)                                                   \
    {                                                                             \
        f32x4 acc0 = {0.f, 0.f, 0.f, 0.f}, acc1 = {0.f, 0.f, 0.f, 0.f};           \
        if (actv) {                                                               \
            _Pragma("unroll") for (int r = 0; r < 4; ++r) {                       \
                acc0[r] = toF32(hX[r]) + bv0;                                     \
                acc1[r] = toF32(hX[4 + r]) + bv1;                                 \
            }                                                                     \
            if ((t) + 2 < T) {                                                    \
                const size_t o = (size_t)((t) + 2) * tstride + base;              \
                _Pragma("unroll") for (int r = 0; r < 4; ++r) {                   \
                    hX[r]     = h[o + (size_t)r * U + n0];                        \
                    hX[4 + r] = h[o + (size_t)r * U + n0 + 16];                   \
                }                                                                 \
            }                                                                     \
        }                                                                         \
        f16x8 af[8];                                                              \
        _Pragma("unroll") for (int kt = 0; kt < 8; ++kt)                          \
            af[kt] = *(const f16x8*)&sbuf[RB][lr][(kt * 32 + lg * 8) ^            \
                                                  ((lr & 7) << 3)];               \
        _Pragma("unroll") for (int kt = 0; kt < 8; ++kt) {                        \
            acc0 = __builtin_amdgcn_mfma_f32_16x16x32_f16(af[kt], bf0[kt],        \
                                                          acc0, 0, 0, 0);         \
            acc1 = __builtin_amdgcn_mfma_f32_16x16x32_f16(af[kt], bf1[kt],        \
                                                          acc1, 0, 0, 0);         \
        }                                                                         \
        float v0[4], v1[4];                                                       \
        _Pragma("unroll") for (int r = 0; r < 4; ++r) {                           \
            v0[r] = tanh_fast(acc0[r]);                                           \
            v1[r] = tanh_fast(acc1[r]);                                           \
        }                                                                         \
        if (actv) {                                                               \
            const size_t o = (size_t)(t) * tstride + base;                        \
            _Pragma("unroll") for (int r = 0; r < 4; ++r) {                       \
                out[o + (size_t)r * U + n0]      = v0[r];                         \
                out[o + (size_t)r * U + n0 + 16] = v1[r];                         \
            }                                                                     \
        }                                                                         \
        _Pragma("unroll") for (int r = 0; r < 4; ++r) {                           \
            const int m = lg * 4 + r;                                             \
            sbuf[WB][m][(n0 + lr) ^ ((m & 7) << 3)]      = (__fp16)v0[r];         \
            sbuf[WB][m][(n0 + 16 + lr) ^ ((m & 7) << 3)] = (__fp16)v1[r];         \
        }                                                                         \
        lds_barrier();                                                            \
    }

    for (int t = 0; t < T; t += 2) {
        RNN_STEP(t,     hE, 0, 1)
        RNN_STEP(t + 1, hO, 1, 0)
    }
#undef RNN_STEP
}

// ---------------------------------------------------------------------------
extern "C" void kernel_launch(void* const* d_in, const int* in_sizes, int n_in,
                              void* d_out, int out_size, void* d_ws, size_t ws_size,
                              hipStream_t stream) {
    const float* in   = (const float*)d_in[0];  // [B, T, F]
    const float* Rm   = (const float*)d_in[1];  // [F, U]
    const float* Wm   = (const float*)d_in[2];  // [U, U]
    const float* bias = (const float*)d_in[3];  // [U]
    const float* x0   = (const float*)d_in[4];  // [U]
    float* out = (float*)d_out;                 // [T, B, U]

    const size_t hElems = (size_t)T * B * U;
    dim3 pgrid(T / 64, U / 64, B);

    if (ws_size >= hElems * sizeof(float)) {
        float* h = (float*)d_ws;
        proj_kernel<float><<<pgrid, 512, 0, stream>>>(in, Rm, h);
        rnn_kernel<float><<<dim3(8), 512, 0, stream>>>(h, Wm, bias, x0, out);
    } else {
        __hip_bfloat16* h = (__hip_bfloat16*)d_ws;
        proj_kernel<__hip_bfloat16><<<pgrid, 512, 0, stream>>>(in, Rm, h);
        rnn_kernel<__hip_bfloat16><<<dim3(8), 512, 0, stream>>>(h, Wm, bias, x0, out);
    }
}

// Round 7
// 986.855 us; speedup vs baseline: 1.1653x; 1.1653x over previous
//
#include <hip/hip_runtime.h>
#include <hip/hip_bf16.h>

// Problem constants (BasicRecurrentLayer): B=64, T=1024, F=128, U=256
constexpr int B = 64;
constexpr int T = 1024;
constexpr int F = 128;
constexpr int U = 256;

typedef __fp16 f16x8 __attribute__((ext_vector_type(8)));
typedef float  f32x4 __attribute__((ext_vector_type(4)));

// ---------------------------------------------------------------------------
// h storage helpers (fp32 if workspace fits 64 MB, else bf16 = 32 MB)
// ---------------------------------------------------------------------------
__device__ __forceinline__ float toF32(float v) { return v; }
__device__ __forceinline__ float toF32(__hip_bfloat16 v) { return __bfloat162float(v); }

__device__ __forceinline__ void store8(float* p, const float* a) {
    ((float4*)p)[0] = make_float4(a[0], a[1], a[2], a[3]);
    ((float4*)p)[1] = make_float4(a[4], a[5], a[6], a[7]);
}
__device__ __forceinline__ void store8(__hip_bfloat16* p, const float* a) {
    unsigned int v[4];
    #pragma unroll
    for (int i = 0; i < 4; ++i) {
        __hip_bfloat16 lo = __float2bfloat16(a[2 * i]);
        __hip_bfloat16 hi = __float2bfloat16(a[2 * i + 1]);
        unsigned short lob = *(unsigned short*)&lo;
        unsigned short hib = *(unsigned short*)&hi;
        v[i] = (unsigned int)lob | ((unsigned int)hib << 16);
    }
    ((uint4*)p)[0] = make_uint4(v[0], v[1], v[2], v[3]);
}

// Exact identity tanh(x) = 1 - 2/(1+e^{2x}); e^{2x} = exp2(x*2*log2(e)).
__device__ __forceinline__ float tanh_fast(float x) {
    float e = __builtin_amdgcn_exp2f(x * 2.885390081777927f);
    float r = __builtin_amdgcn_rcpf(1.0f + e);
    return fmaf(-2.0f, r, 1.0f);
}

// lgkmcnt(0) only (vmcnt=63, expcnt=7 -> no wait): 0xC07F. Raw barrier that
// does NOT drain vmcnt, so h-prefetch / out-stores stay in flight across it.
__device__ __forceinline__ void lds_barrier() {
    __builtin_amdgcn_s_waitcnt(0xC07F);
    asm volatile("" ::: "memory");
    __builtin_amdgcn_s_barrier();
    asm volatile("" ::: "memory");
}

// ---------------------------------------------------------------------------
// Kernel 1: projection  h[t, b, u] = sum_f inputs[b, t, f] * R[f, u] + bias[u]
// (bias pre-folded here so the rnn step's C-init is a pure convert).
// Grid (T/64, U/64, B), 512 threads (8 waves). Round-0 structure verbatim.
// ---------------------------------------------------------------------------
template <typename HT>
__global__ __launch_bounds__(512, 2) void proj_kernel(
    const float* __restrict__ in,   // [B, T, F]
    const float* __restrict__ Rm,   // [F, U]
    const float* __restrict__ bias, // [U]
    HT* __restrict__ h)             // [T, B, U]  (h + bias)
{
    const int t0   = blockIdx.x * 64;
    const int u0b  = blockIdx.y * 64;
    const int b    = blockIdx.z;
    const int tid  = threadIdx.x;
    const int lane = tid & 63;      // = r (t-row within tile)
    const int wv   = tid >> 6;      // 0..7
    const int u0   = __builtin_amdgcn_readfirstlane(u0b + wv * 8);

    __shared__ float4 a4[64 * 32];  // 32 KB, swizzled

    const float4* src = (const float4*)(in + ((size_t)b * T + t0) * F);
    #pragma unroll
    for (int it = 0; it < 4; ++it) {
        int f  = tid + it * 512;        // 0..2047 coalesced
        int r  = f >> 5;
        int k4 = f & 31;
        a4[(r << 5) | (k4 ^ (r & 31))] = src[f];
    }
    __syncthreads();

    const float* Rp = Rm + u0;      // wave-uniform -> scalar loads
    float acc[8];
    #pragma unroll
    for (int j = 0; j < 8; ++j) acc[j] = 0.f;

    float ra[32], rb[32];           // uniform (SGPR) ping-pong R buffers
    #pragma unroll
    for (int kk = 0; kk < 4; ++kk)
        #pragma unroll
        for (int j = 0; j < 8; ++j)
            ra[kk * 8 + j] = Rp[(size_t)kk * U + j];

    const int r = lane;
    #pragma unroll
    for (int k4 = 0; k4 < 32; k4 += 2) {
        #pragma unroll
        for (int kk = 0; kk < 4; ++kk)
            #pragma unroll
            for (int j = 0; j < 8; ++j)
                rb[kk * 8 + j] = Rp[(size_t)((k4 + 1) * 4 + kk) * U + j];

        float4 av = a4[(r << 5) | (k4 ^ (r & 31))];
        #pragma unroll
        for (int j = 0; j < 8; ++j) {
            acc[j] = fmaf(av.x, ra[0 * 8 + j], acc[j]);
            acc[j] = fmaf(av.y, ra[1 * 8 + j], acc[j]);
            acc[j] = fmaf(av.z, ra[2 * 8 + j], acc[j]);
            acc[j] = fmaf(av.w, ra[3 * 8 + j], acc[j]);
        }

        if (k4 + 2 < 32) {
            #pragma unroll
            for (int kk = 0; kk < 4; ++kk)
                #pragma unroll
                for (int j = 0; j < 8; ++j)
                    ra[kk * 8 + j] = Rp[(size_t)((k4 + 2) * 4 + kk) * U + j];
        }

        float4 av2 = a4[(r << 5) | ((k4 + 1) ^ (r & 31))];
        #pragma unroll
        for (int j = 0; j < 8; ++j) {
            acc[j] = fmaf(av2.x, rb[0 * 8 + j], acc[j]);
            acc[j] = fmaf(av2.y, rb[1 * 8 + j], acc[j]);
            acc[j] = fmaf(av2.z, rb[2 * 8 + j], acc[j]);
            acc[j] = fmaf(av2.w, rb[3 * 8 + j], acc[j]);
        }
    }

    // fold bias (wave-uniform scalar loads)
    const float* bp = bias + u0;
    #pragma unroll
    for (int j = 0; j < 8; ++j) acc[j] += bp[j];

    HT* hp = h + ((size_t)(t0 + r) * B + b) * U + u0;
    store8(hp, acc);
}

// ---------------------------------------------------------------------------
// Kernel 2: recurrence via MFMA. Grid 4 (16 REAL batch rows per block — no
// pad waste), 512 threads = 8 waves; wave wv owns cols [32wv, 32wv+32)
// (N-tiles nt=0,1). W B-fragments preloaded (verified layout, round 5).
//
// State S[16][256] fp16 lives in LDS in A-FRAGMENT ORDER with a bank-perm:
//   fp16 index within k-tile kt block (1 KB): perm(rl)*8 + j, where the A-frag
//   reader (lane rl, elem j) needs A[row=rl&15][k=kt*32+(rl>>4)*8+j] and
//   perm(rl) = bits[rl3,rl4,rl2,rl0,rl1,rl5].
//   * Reads: lane l does ds_read_b128 at kt*1024 + perm(l)*16 — bijective
//     lane->16B slot = canonical conflict-free pattern.
//   * Writes: C/D value (nt,reg) of lane l lands at byte
//       wv*1024 + [((l>>5)&1)*16 + ((l>>3)&1)*32 + ((l>>4)&1)*64 + (l&7)*2]
//       + reg*128 + nt*512
//     = one lane base + compile-time immediates; per-instruction lanes cover
//     all 32 banks (write pairs share a dword -> merged). Conflict-free.
//   (Worked check: writer l=21,nt=1,reg=2 -> byte 842; reader rl=38 (pl=52),
//    j=5 -> 52*16+10 = 842. Matches.)
//
// ROUND-7 FIX: consume hX into the accumulators BEFORE the t+2 prefetch
// overwrites hX (round 6 had the order swapped -> used h[t+2] for step t).
//
// Per step: 8 ds_read_b128, 16 MFMA in 4 chains of 4 (split accumulators),
// h-prefetch (t+2, even/odd reg sets), tanh, 8 ds_write_b16 (imm offsets),
// 8 out stores (imm offsets), ONE lgkm-only barrier. h is pre-biased by proj.
// ---------------------------------------------------------------------------
template <typename HT>
__global__ __launch_bounds__(512, 1) void rnn_kernel(
    const HT* __restrict__ h,        // [T, B, U] (pre-biased)
    const float* __restrict__ Wm,    // [U, U]
    const float* __restrict__ x0,    // [U]
    float* __restrict__ out)         // [T, B, U]
{
    const int bk  = blockIdx.x;       // batch rows bk*16 .. bk*16+15
    const int tid = threadIdx.x;
    const int l   = tid & 63;
    const int wv  = tid >> 6;         // 0..7
    const int lr  = l & 15;
    const int lg  = l >> 4;           // 0..3
    const int n0  = wv * 32;

    __shared__ __fp16 sbuf[2][8][64][8];   // 16 KB: [buf][kt][slot][j]

    // B fragments: bf{nt}[kt][jj] = W[kt*32 + lg*8 + jj][n0 + nt*16 + lr]
    f16x8 bf0[8], bf1[8];
    #pragma unroll
    for (int kt = 0; kt < 8; ++kt) {
        #pragma unroll
        for (int jj = 0; jj < 8; ++jj) {
            const size_t k = (size_t)(kt * 32 + lg * 8 + jj);
            bf0[kt][jj] = (__fp16)Wm[k * U + n0 + lr];
            bf1[kt][jj] = (__fp16)Wm[k * U + n0 + 16 + lr];
        }
    }

    // per-lane LDS offsets
    const int pl = ((l >> 3) & 1) | (((l >> 4) & 1) << 1) | (((l >> 2) & 1) << 2)
                 | ((l & 1) << 3) | (((l >> 1) & 1) << 4) | (l & 32);
    const int rdoff = pl * 16;                                   // bytes in kt-block
    const int wboff = ((l >> 5) & 1) * 16 + ((l >> 3) & 1) * 32
                    + ((l >> 4) & 1) * 64 + (l & 7) * 2 + wv * 1024;  // bytes in buf

    // init S = x0 into buf 0 (afrag order): thread (wv,l) covers kt=wv slots
    #pragma unroll
    for (int j = 0; j < 8; ++j)
        sbuf[0][wv][pl][j] = (__fp16)x0[wv * 32 + lg * 8 + j];
    __syncthreads();

    const size_t tstride = (size_t)B * U;                        // 16384
    const HT*    hb = h   + ((size_t)(bk * 16 + lg * 4)) * U + n0 + lr;
    float*       op = out + ((size_t)(bk * 16 + lg * 4)) * U + n0 + lr;

    // h prefetch, 2 steps deep; layout [nt*4 + reg]
    HT hE[8], hO[8];
    #pragma unroll
    for (int rg = 0; rg < 4; ++rg) {
        hE[rg]     = hb[(size_t)rg * U];
        hE[4 + rg] = hb[(size_t)rg * U + 16];
        hO[rg]     = hb[tstride + (size_t)rg * U];
        hO[4 + rg] = hb[tstride + (size_t)rg * U + 16];
    }

#define RNN_STEP(t, hX, RB, WB)                                                   \
    {                                                                             \
        /* consume h[t] FIRST (round-7 fix), then it's safe to prefetch t+2 */    \
        f32x4 a0a, a0b = {0.f, 0.f, 0.f, 0.f}, a1a, a1b = {0.f, 0.f, 0.f, 0.f};  \
        _Pragma("unroll") for (int rg = 0; rg < 4; ++rg) {                        \
            a0a[rg] = toF32(hX[rg]);                                              \
            a1a[rg] = toF32(hX[4 + rg]);                                          \
        }                                                                         \
        f16x8 af[8];                                                              \
        _Pragma("unroll") for (int kt = 0; kt < 8; ++kt)                          \
            af[kt] = *(const f16x8*)((const char*)&sbuf[RB][kt][0][0] + rdoff);   \
        if ((t) + 2 < T) {                                                        \
            const HT* pb = hb + (size_t)((t) + 2) * tstride;                      \
            _Pragma("unroll") for (int rg = 0; rg < 4; ++rg) {                    \
                hX[rg]     = pb[(size_t)rg * U];                                  \
                hX[4 + rg] = pb[(size_t)rg * U + 16];                             \
            }                                                                     \
        }                                                                         \
        _Pragma("unroll") for (int kt = 0; kt < 4; ++kt) {                        \
            a0a = __builtin_amdgcn_mfma_f32_16x16x32_f16(af[kt], bf0[kt], a0a, 0, 0, 0); \
            a1a = __builtin_amdgcn_mfma_f32_16x16x32_f16(af[kt], bf1[kt], a1a, 0, 0, 0); \
        }                                                                         \
        _Pragma("unroll") for (int kt = 4; kt < 8; ++kt) {                        \
            a0b = __builtin_amdgcn_mfma_f32_16x16x32_f16(af[kt], bf0[kt], a0b, 0, 0, 0); \
            a1b = __builtin_amdgcn_mfma_f32_16x16x32_f16(af[kt], bf1[kt], a1b, 0, 0, 0); \
        }                                                                         \
        float v0[4], v1[4];                                                       \
        _Pragma("unroll") for (int rg = 0; rg < 4; ++rg) {                        \
            v0[rg] = tanh_fast(a0a[rg] + a0b[rg]);                                \
            v1[rg] = tanh_fast(a1a[rg] + a1b[rg]);                                \
        }                                                                         \
        char* wp = (char*)&sbuf[WB][0][0][0] + wboff;                             \
        _Pragma("unroll") for (int rg = 0; rg < 4; ++rg) {                        \
            *(__fp16*)(wp + rg * 128)       = (__fp16)v0[rg];                     \
            *(__fp16*)(wp + rg * 128 + 512) = (__fp16)v1[rg];                     \
        }                                                                         \
        float* ob = op + (size_t)(t) * tstride;                                   \
        _Pragma("unroll") for (int rg = 0; rg < 4; ++rg) {                        \
            ob[(size_t)rg * U]      = v0[rg];                                     \
            ob[(size_t)rg * U + 16] = v1[rg];                                     \
        }                                                                         \
        lds_barrier();                                                            \
    }

    for (int t = 0; t < T; t += 2) {
        RNN_STEP(t,     hE, 0, 1)
        RNN_STEP(t + 1, hO, 1, 0)
    }
#undef RNN_STEP
}

// ---------------------------------------------------------------------------
extern "C" void kernel_launch(void* const* d_in, const int* in_sizes, int n_in,
                              void* d_out, int out_size, void* d_ws, size_t ws_size,
                              hipStream_t stream) {
    const float* in   = (const float*)d_in[0];  // [B, T, F]
    const float* Rm   = (const float*)d_in[1];  // [F, U]
    const float* Wm   = (const float*)d_in[2];  // [U, U]
    const float* bias = (const float*)d_in[3];  // [U]
    const float* x0   = (const float*)d_in[4];  // [U]
    float* out = (float*)d_out;                 // [T, B, U]

    const size_t hElems = (size_t)T * B * U;
    dim3 pgrid(T / 64, U / 64, B);

    if (ws_size >= hElems * sizeof(float)) {
        float* h = (float*)d_ws;
        proj_kernel<float><<<pgrid, 512, 0, stream>>>(in, Rm, bias, h);
        rnn_kernel<float><<<dim3(B / 16), 512, 0, stream>>>(h, Wm, x0, out);
    } else {
        __hip_bfloat16* h = (__hip_bfloat16*)d_ws;
        proj_kernel<__hip_bfloat16><<<pgrid, 512, 0, stream>>>(in, Rm, bias, h);
        rnn_kernel<__hip_bfloat16><<<dim3(B / 16), 512, 0, stream>>>(h, Wm, x0, out);
    }
}

// Round 9
// 978.721 us; speedup vs baseline: 1.1750x; 1.0083x over previous
//
#include <hip/hip_runtime.h>
#include <hip/hip_bf16.h>

// Problem constants (BasicRecurrentLayer): B=64, T=1024, F=128, U=256
constexpr int B = 64;
constexpr int T = 1024;
constexpr int F = 128;
constexpr int U = 256;

typedef __fp16 f16x8 __attribute__((ext_vector_type(8)));
typedef float  f32x4 __attribute__((ext_vector_type(4)));

// ---------------------------------------------------------------------------
// h storage helpers (fp32 if workspace fits 64 MB, else bf16 = 32 MB)
// ---------------------------------------------------------------------------
__device__ __forceinline__ float toF32(float v) { return v; }
__device__ __forceinline__ float toF32(__hip_bfloat16 v) { return __bfloat162float(v); }

__device__ __forceinline__ void store8(float* p, const float* a) {
    ((float4*)p)[0] = make_float4(a[0], a[1], a[2], a[3]);
    ((float4*)p)[1] = make_float4(a[4], a[5], a[6], a[7]);
}
__device__ __forceinline__ void store8(__hip_bfloat16* p, const float* a) {
    unsigned int v[4];
    #pragma unroll
    for (int i = 0; i < 4; ++i) {
        __hip_bfloat16 lo = __float2bfloat16(a[2 * i]);
        __hip_bfloat16 hi = __float2bfloat16(a[2 * i + 1]);
        unsigned short lob = *(unsigned short*)&lo;
        unsigned short hib = *(unsigned short*)&hi;
        v[i] = (unsigned int)lob | ((unsigned int)hib << 16);
    }
    ((uint4*)p)[0] = make_uint4(v[0], v[1], v[2], v[3]);
}

// Exact identity tanh(x) = 1 - 2/(1+e^{2x}); e^{2x} = exp2(x*2*log2(e)).
__device__ __forceinline__ float tanh_fast(float x) {
    float e = __builtin_amdgcn_exp2f(x * 2.885390081777927f);
    float r = __builtin_amdgcn_rcpf(1.0f + e);
    return fmaf(-2.0f, r, 1.0f);
}

// lgkmcnt(0) only (vmcnt=63, expcnt=7 -> no wait): 0xC07F. Raw barrier that
// does NOT drain vmcnt, so h-prefetch / out-stores stay in flight across it.
__device__ __forceinline__ void lds_barrier() {
    __builtin_amdgcn_s_waitcnt(0xC07F);
    asm volatile("" ::: "memory");
    __builtin_amdgcn_s_barrier();
    asm volatile("" ::: "memory");
}

// ---------------------------------------------------------------------------
// Kernel 1: projection  h[t, b, u] = sum_f inputs[b, t, f] * R[f, u] + bias[u]
// (bias pre-folded here so the rnn step's C-init is a pure convert).
// Grid (T/64, U/64, B), 512 threads (8 waves). Round-0 structure verbatim.
// ---------------------------------------------------------------------------
template <typename HT>
__global__ __launch_bounds__(512, 2) void proj_kernel(
    const float* __restrict__ in,   // [B, T, F]
    const float* __restrict__ Rm,   // [F, U]
    const float* __restrict__ bias, // [U]
    HT* __restrict__ h)             // [T, B, U]  (h + bias)
{
    const int t0   = blockIdx.x * 64;
    const int u0b  = blockIdx.y * 64;
    const int b    = blockIdx.z;
    const int tid  = threadIdx.x;
    const int lane = tid & 63;      // = r (t-row within tile)
    const int wv   = tid >> 6;      // 0..7
    const int u0   = __builtin_amdgcn_readfirstlane(u0b + wv * 8);

    __shared__ float4 a4[64 * 32];  // 32 KB, swizzled

    const float4* src = (const float4*)(in + ((size_t)b * T + t0) * F);
    #pragma unroll
    for (int it = 0; it < 4; ++it) {
        int f  = tid + it * 512;        // 0..2047 coalesced
        int r  = f >> 5;
        int k4 = f & 31;
        a4[(r << 5) | (k4 ^ (r & 31))] = src[f];
    }
    __syncthreads();

    const float* Rp = Rm + u0;      // wave-uniform -> scalar loads
    float acc[8];
    #pragma unroll
    for (int j = 0; j < 8; ++j) acc[j] = 0.f;

    float ra[32], rb[32];           // uniform (SGPR) ping-pong R buffers
    #pragma unroll
    for (int kk = 0; kk < 4; ++kk)
        #pragma unroll
        for (int j = 0; j < 8; ++j)
            ra[kk * 8 + j] = Rp[(size_t)kk * U + j];

    const int r = lane;
    #pragma unroll
    for (int k4 = 0; k4 < 32; k4 += 2) {
        #pragma unroll
        for (int kk = 0; kk < 4; ++kk)
            #pragma unroll
            for (int j = 0; j < 8; ++j)
                rb[kk * 8 + j] = Rp[(size_t)((k4 + 1) * 4 + kk) * U + j];

        float4 av = a4[(r << 5) | (k4 ^ (r & 31))];
        #pragma unroll
        for (int j = 0; j < 8; ++j) {
            acc[j] = fmaf(av.x, ra[0 * 8 + j], acc[j]);
            acc[j] = fmaf(av.y, ra[1 * 8 + j], acc[j]);
            acc[j] = fmaf(av.z, ra[2 * 8 + j], acc[j]);
            acc[j] = fmaf(av.w, ra[3 * 8 + j], acc[j]);
        }

        if (k4 + 2 < 32) {
            #pragma unroll
            for (int kk = 0; kk < 4; ++kk)
                #pragma unroll
                for (int j = 0; j < 8; ++j)
                    ra[kk * 8 + j] = Rp[(size_t)((k4 + 2) * 4 + kk) * U + j];
        }

        float4 av2 = a4[(r << 5) | ((k4 + 1) ^ (r & 31))];
        #pragma unroll
        for (int j = 0; j < 8; ++j) {
            acc[j] = fmaf(av2.x, rb[0 * 8 + j], acc[j]);
            acc[j] = fmaf(av2.y, rb[1 * 8 + j], acc[j]);
            acc[j] = fmaf(av2.z, rb[2 * 8 + j], acc[j]);
            acc[j] = fmaf(av2.w, rb[3 * 8 + j], acc[j]);
        }
    }

    // fold bias (wave-uniform scalar loads)
    const float* bp = bias + u0;
    #pragma unroll
    for (int j = 0; j < 8; ++j) acc[j] += bp[j];

    HT* hp = h + ((size_t)(t0 + r) * B + b) * U + u0;
    store8(hp, acc);
}

// ---------------------------------------------------------------------------
// Kernel 2: recurrence via MFMA. Grid 8 x 256 threads (4 waves, 1/SIMD).
// Block bk owns 8 REAL batch rows mapped to A-rows r with (r&3)<2:
//   batch = bk*8 + 2*lg + reg   (lg = lane>>4, reg = C/D element 0 or 1)
// so C/D elements 2,3 are pure pad: no tanh/cvt/ds_write/store for them,
// pad A-rows are never written (MFMA rows are independent -> garbage stays
// in pad rows). Wave wv owns cols [64wv, 64wv+64) = N-tiles nt 0..3.
//
// LDS state layout [buf][kt][slot][j] (fp16, 16 KB), slot map for X[row][k],
// k = kt*32 + koff*8 + j, row bits r0..r3, koff bits k0,k1:
//   slot = (r0^r2) | (r1^r3)<<1 | (k0^r0^r1)<<2 | r0<<3 | r1<<4 | k1<<5
// * Read (A-frag, lane rl: row=rl&15, koff=rl>>4): slot(rl) precomputed;
//   each b128 quarter-wave covers every bank-residue (slot mod 8) EXACTLY
//   twice (enumerated) -> 2-way = free.
// * Write (C/D (nt,reg) of lane l: row=lg*4+reg, col=n0+nt*16+lr):
//   kt = 2wv + (nt>>1), koff = 2(nt&1) + lr3, j = lr&7 ->
//   byte = 2wv*1024 + [ (reg^lg0) | ((lg>>1)&1)<<1 | (lr3^reg)<<2 | reg<<3 ]*16
//          + (lr&7)*2   + (nt>>1)*1024 + (nt&1)*512   (immediates)
//   8 distinct slot-residues per instruction = all 32 banks -> conflict-free.
//   (Worked example wv=1,l=21,nt=2,reg=1: writer byte matches reader inverse.)
//
// Per step/wave: 8 h-cvt C-init, 8 ds_read_b128, 8 prefetch loads (t+2),
// 32 MFMA (8 chains of 4), 8 tanh, 8 cvt, 8 ds_write_b16, 8 out stores,
// ONE lgkm-only barrier. h pre-biased by proj.
// ---------------------------------------------------------------------------
template <typename HT>
__global__ __launch_bounds__(256, 1) void rnn_kernel(
    const HT* __restrict__ h,        // [T, B, U] (pre-biased)
    const float* __restrict__ Wm,    // [U, U]
    const float* __restrict__ x0,    // [U]
    float* __restrict__ out)         // [T, B, U]
{
    const int bk  = blockIdx.x;       // batch rows bk*8 .. bk*8+7
    const int tid = threadIdx.x;
    const int l   = tid & 63;
    const int wv  = tid >> 6;         // 0..3
    const int lr  = l & 15;
    const int lg  = l >> 4;           // 0..3
    const int n0  = wv * 64;

    __shared__ __fp16 sbuf[2][8][64][8];   // 16 KB: [buf][kt][slot][j]

    // zero both buffers (pad rows stay 0 forever)
    {
        uint4 z = make_uint4(0u, 0u, 0u, 0u);
        uint4* p = (uint4*)sbuf;
        #pragma unroll
        for (int i = 0; i < 4; ++i) p[tid + i * 256] = z;
    }

    // B fragments: bf[nt][kt][jj] = W[kt*32 + lg*8 + jj][n0 + nt*16 + lr]
    f16x8 bf[4][8];
    #pragma unroll
    for (int nt = 0; nt < 4; ++nt)
        #pragma unroll
        for (int kt = 0; kt < 8; ++kt)
            #pragma unroll
            for (int jj = 0; jj < 8; ++jj)
                bf[nt][kt][jj] =
                    (__fp16)Wm[(size_t)(kt * 32 + lg * 8 + jj) * U + n0 + nt * 16 + lr];

    // A-frag read slot (lane l: row = l&15 -> bits l0..l3; koff -> l4,l5)
    const int rslot = ((l ^ (l >> 2)) & 1)
                    | (((l >> 1) ^ (l >> 3)) & 1) << 1
                    | (((l >> 4) ^ l ^ (l >> 1)) & 1) << 2
                    | ((l & 1) << 3) | (((l >> 1) & 1) << 4) | (((l >> 5) & 1) << 5);
    const int rdoff = rslot * 16;     // bytes within a kt-block

    // write byte base per reg (nt=0 terms; nt folds into immediates)
    int wboff[2];
    #pragma unroll
    for (int reg = 0; reg < 2; ++reg) {
        int b0 = reg ^ (lg & 1);
        int b1 = (lg >> 1) & 1;
        int b2 = ((lr >> 3) & 1) ^ reg;
        int slot = b0 | (b1 << 1) | (b2 << 2) | (reg << 3);
        wboff[reg] = (2 * wv) * 1024 + slot * 16 + (lr & 7) * 2;
    }

    __syncthreads();    // zero-init visible before x0 fill overwrites real rows

    // x0 into buf0 real rows ((row&3)<2); invert slot map per (kt, s)
    #pragma unroll
    for (int i = 0; i < 2; ++i) {
        int idx = tid + i * 256;      // 0..511 over [kt][slot]
        int kt = idx >> 6, s = idx & 63;
        int r0 = (s >> 3) & 1, r1 = (s >> 4) & 1, k1 = (s >> 5) & 1;
        int r2 = (s & 1) ^ r0, r3 = ((s >> 1) & 1) ^ r1;
        int k0 = ((s >> 2) & 1) ^ r0 ^ r1;
        int row = r0 + 2 * r1 + 4 * r2 + 8 * r3;
        if ((row & 3) < 2) {
            int kb = kt * 32 + (k0 + 2 * k1) * 8;
            #pragma unroll
            for (int j = 0; j < 8; ++j)
                sbuf[0][kt][s][j] = (__fp16)x0[kb + j];
        }
    }
    __syncthreads();

    const size_t tstride = (size_t)B * U;                       // 16384
    const HT*    hb = h   + (size_t)(bk * 8 + 2 * lg) * U + n0 + lr;
    float*       op = out + (size_t)(bk * 8 + 2 * lg) * U + n0 + lr;

    // h prefetch, 2 steps deep; layout [nt*2 + reg]
    HT hE[8], hO[8];
    #pragma unroll
    for (int nt = 0; nt < 4; ++nt) {
        #pragma unroll
        for (int reg = 0; reg < 2; ++reg) {
            hE[nt * 2 + reg] = hb[(size_t)reg * U + nt * 16];
            hO[nt * 2 + reg] = hb[tstride + (size_t)reg * U + nt * 16];
        }
    }

#define RNN_STEP(t, hX, RB, WB)                                                   \
    {                                                                             \
        /* consume h[t] into C-init FIRST, then prefetch t+2 (round-7 lesson) */  \
        f32x4 aA[4], aB[4];                                                       \
        _Pragma("unroll") for (int nt = 0; nt < 4; ++nt) {                        \
            aA[nt][0] = toF32(hX[nt * 2 + 0]);                                    \
            aA[nt][1] = toF32(hX[nt * 2 + 1]);                                    \
            aA[nt][2] = 0.f; aA[nt][3] = 0.f;                                     \
            aB[nt][0] = 0.f; aB[nt][1] = 0.f; aB[nt][2] = 0.f; aB[nt][3] = 0.f;   \
        }                                                                         \
        if ((t) + 2 < T) {                                                        \
            const HT* pb = hb + (size_t)((t) + 2) * tstride;                      \
            _Pragma("unroll") for (int nt = 0; nt < 4; ++nt)                      \
                _Pragma("unroll") for (int reg = 0; reg < 2; ++reg)               \
                    hX[nt * 2 + reg] = pb[(size_t)reg * U + nt * 16];             \
        }                                                                         \
        f16x8 af[8];                                                              \
        _Pragma("unroll") for (int kt = 0; kt < 8; ++kt)                          \
            af[kt] = *(const f16x8*)((const char*)sbuf + (RB) * 8192 +            \
                                     kt * 1024 + rdoff);                          \
        _Pragma("unroll") for (int kt = 0; kt < 4; ++kt)                          \
            _Pragma("unroll") for (int nt = 0; nt < 4; ++nt)                      \
                aA[nt] = __builtin_amdgcn_mfma_f32_16x16x32_f16(af[kt],           \
                             bf[nt][kt], aA[nt], 0, 0, 0);                        \
        _Pragma("unroll") for (int kt = 4; kt < 8; ++kt)                          \
            _Pragma("unroll") for (int nt = 0; nt < 4; ++nt)                      \
                aB[nt] = __builtin_amdgcn_mfma_f32_16x16x32_f16(af[kt],           \
                             bf[nt][kt], aB[nt], 0, 0, 0);                        \
        float v[4][2];                                                            \
        _Pragma("unroll") for (int nt = 0; nt < 4; ++nt)                          \
            _Pragma("unroll") for (int reg = 0; reg < 2; ++reg)                   \
                v[nt][reg] = tanh_fast(aA[nt][reg] + aB[nt][reg]);                \
        char* wp = (char*)sbuf + (WB) * 8192;                                     \
        _Pragma("unroll") for (int nt = 0; nt < 4; ++nt)                          \
            _Pragma("unroll") for (int reg = 0; reg < 2; ++reg)                   \
                *(__fp16*)(wp + wboff[reg] + (nt >> 1) * 1024 + (nt & 1) * 512)   \
                    = (__fp16)v[nt][reg];                                         \
        float* ob = op + (size_t)(t) * tstride;                                   \
        _Pragma("unroll") for (int nt = 0; nt < 4; ++nt)                          \
            _Pragma("unroll") for (int reg = 0; reg < 2; ++reg)                   \
                ob[(size_t)reg * U + nt * 16] = v[nt][reg];                       \
        lds_barrier();                                                            \
    }

    for (int t = 0; t < T; t += 2) {
        RNN_STEP(t,     hE, 0, 1)
        RNN_STEP(t + 1, hO, 1, 0)
    }
#undef RNN_STEP
}

// ---------------------------------------------------------------------------
extern "C" void kernel_launch(void* const* d_in, const int* in_sizes, int n_in,
                              void* d_out, int out_size, void* d_ws, size_t ws_size,
                              hipStream_t stream) {
    const float* in   = (const float*)d_in[0];  // [B, T, F]
    const float* Rm   = (const float*)d_in[1];  // [F, U]
    const float* Wm   = (const float*)d_in[2];  // [U, U]
    const float* bias = (const float*)d_in[3];  // [U]
    const float* x0   = (const float*)d_in[4];  // [U]
    float* out = (float*)d_out;                 // [T, B, U]

    const size_t hElems = (size_t)T * B * U;
    dim3 pgrid(T / 64, U / 64, B);

    if (ws_size >= hElems * sizeof(float)) {
        float* h = (float*)d_ws;
        proj_kernel<float><<<pgrid, 512, 0, stream>>>(in, Rm, bias, h);
        rnn_kernel<float><<<dim3(B / 8), 256, 0, stream>>>(h, Wm, x0, out);
    } else {
        __hip_bfloat16* h = (__hip_bfloat16*)d_ws;
        proj_kernel<__hip_bfloat16><<<pgrid, 512, 0, stream>>>(in, Rm, bias, h);
        rnn_kernel<__hip_bfloat16><<<dim3(B / 8), 256, 0, stream>>>(h, Wm, x0, out);
    }
}